// Round 1
// baseline (12690.884 us; speedup 1.0000x reference)
//
#include <hip/hip_runtime.h>
#include <hip/hip_bf16.h>
#include <math.h>

#define BIGF 1e4f

// ---------------- EDT row pass: per-row 1D nearest distance (ones & zeros) --
__global__ __launch_bounds__(64)
void edt_rows_k(const float* __restrict__ logits, const int* __restrict__ truem,
                float* __restrict__ g2o, float* __restrict__ g2z)
{
    int blk = blockIdx.x;
    int a = blk / 384, row = blk % 384;
    int lane = threadIdx.x;
    int j0 = lane * 6;
    float mk[6];
    if (a < 2) {
        const float* l0 = logits + (size_t)a * 2 * 147456 + (size_t)row * 384;
        const float* l1 = l0 + 147456;
        #pragma unroll
        for (int u = 0; u < 6; ++u) mk[u] = (l1[j0+u] > l0[j0+u]) ? 1.f : 0.f;
    } else {
        const int* t = truem + (size_t)(a - 2) * 147456 + (size_t)row * 384;
        #pragma unroll
        for (int u = 0; u < 6; ++u) mk[u] = (t[j0+u] != 0) ? 1.f : 0.f;
    }
    float lo[6], lz[6], ro[6], rz[6];
    float run_lo = -BIGF, run_lz = -BIGF;
    #pragma unroll
    for (int u = 0; u < 6; ++u) {
        float jf = (float)(j0 + u);
        if (mk[u] > 0.5f) run_lo = jf; else run_lz = jf;
        lo[u] = run_lo; lz[u] = run_lz;
    }
    float inc_o = run_lo, inc_z = run_lz;
    for (int off = 1; off < 64; off <<= 1) {
        float to = __shfl_up(inc_o, off), tz = __shfl_up(inc_z, off);
        if (lane >= off) { inc_o = fmaxf(inc_o, to); inc_z = fmaxf(inc_z, tz); }
    }
    float ex_o = __shfl_up(inc_o, 1); if (lane == 0) ex_o = -BIGF;
    float ex_z = __shfl_up(inc_z, 1); if (lane == 0) ex_z = -BIGF;

    float run_ro = BIGF, run_rz = BIGF;
    #pragma unroll
    for (int u = 5; u >= 0; --u) {
        float jf = (float)(j0 + u);
        if (mk[u] > 0.5f) run_ro = jf; else run_rz = jf;
        ro[u] = run_ro; rz[u] = run_rz;
    }
    float in2_o = run_ro, in2_z = run_rz;
    for (int off = 1; off < 64; off <<= 1) {
        float to = __shfl_down(in2_o, off), tz = __shfl_down(in2_z, off);
        if (lane + off < 64) { in2_o = fminf(in2_o, to); in2_z = fminf(in2_z, tz); }
    }
    float sx_o = __shfl_down(in2_o, 1); if (lane == 63) sx_o = BIGF;
    float sx_z = __shfl_down(in2_z, 1); if (lane == 63) sx_z = BIGF;

    size_t ob = (size_t)a * 147456 + (size_t)row * 384;
    #pragma unroll
    for (int u = 0; u < 6; ++u) {
        float jf = (float)(j0 + u);
        float dlo = jf - fmaxf(lo[u], ex_o);
        float dro = fminf(ro[u], sx_o) - jf;
        float go = fminf(fminf(dlo, dro), BIGF);
        float dlz = jf - fmaxf(lz[u], ex_z);
        float drz = fminf(rz[u], sx_z) - jf;
        float gz = fminf(fminf(dlz, drz), BIGF);
        g2o[ob + j0 + u] = go * go;
        g2z[ob + j0 + u] = gz * gz;
    }
}

// ---------------- EDT column pass: min-plus over rows, emit signed distance --
__global__ __launch_bounds__(256)
void edt_cols_k(const float* __restrict__ g2o, const float* __restrict__ g2z,
                float* __restrict__ sdm)
{
    int a = blockIdx.y;
    int w0 = blockIdx.x * 8;
    __shared__ float so[384][8];
    __shared__ float sz[384][8];
    int tid = threadIdx.x;
    for (int h = 0; h < 12; ++h) {
        int lin = tid + 256 * h;           // 0..3071
        int ip = lin >> 3, ww = lin & 7;
        so[ip][ww] = g2o[(size_t)a * 147456 + (size_t)ip * 384 + w0 + ww];
        sz[ip][ww] = g2z[(size_t)a * 147456 + (size_t)ip * 384 + w0 + ww];
    }
    __syncthreads();
    int w = tid & 7, ib = tid >> 3;        // ib 0..31
    float vo[12], vz[12];
    #pragma unroll
    for (int r = 0; r < 12; ++r) { vo[r] = 3.4e38f; vz[r] = 3.4e38f; }
    for (int ip = 0; ip < 384; ++ip) {
        float go = so[ip][w], gz = sz[ip][w];
        #pragma unroll
        for (int r = 0; r < 12; ++r) {
            float d = (float)(ib + 32 * r - ip);
            float dd = d * d;
            vo[r] = fminf(vo[r], dd + go);
            vz[r] = fminf(vz[r], dd + gz);
        }
    }
    #pragma unroll
    for (int r = 0; r < 12; ++r) {
        sdm[(size_t)a * 147456 + (size_t)(ib + 32 * r) * 384 + w0 + w] =
            sqrtf(vo[r]) - sqrtf(vz[r]);
    }
}

// ---------------- channel-reduced patch weight ------------------------------
__global__ void weff_k(const float* __restrict__ pw, float* __restrict__ W)
{
    int i = blockIdx.x * 256 + threadIdx.x;
    if (i < 196608) W[i] = pw[i] + pw[i + 196608] + pw[i + 393216];
}

// ---------------- gather patch vectors [4*576, 256] -------------------------
__global__ void pvec_k(const float* __restrict__ sdm, float* __restrict__ pvec)
{
    int idx = blockIdx.x * 256 + threadIdx.x;   // 589824 total
    int cc = idx & 15, r = (idx >> 4) & 15, p = idx >> 8;
    int px = p % 24, py = (p / 24) % 24, aa = p / 576;
    pvec[idx] = sdm[(size_t)aa * 147456 + (size_t)(py * 16 + r) * 384 + px * 16 + cc];
}

// ---------------- cls + pos assembly ---------------------------------------
__global__ void addpos_k(const float* __restrict__ tok, const float* __restrict__ cls,
                         const float* __restrict__ pos, float* __restrict__ X)
{
    int idx = blockIdx.x * 256 + threadIdx.x;
    if (idx >= 1772544) return;
    int d = idx % 768;
    int t = (idx / 768) % 577;
    int img = idx / (768 * 577);
    float v;
    if (t == 0) v = cls[d] + pos[d];
    else v = tok[((size_t)img * 576 + (t - 1)) * 768 + d] + pos[(size_t)t * 768 + d];
    X[idx] = v;
}

// ---------------- LayerNorm (rows of 768) -----------------------------------
__global__ __launch_bounds__(256)
void ln_k(const float* __restrict__ X, const float* __restrict__ g,
          const float* __restrict__ b, float* __restrict__ Y)
{
    int row = blockIdx.x;
    const float* x = X + (size_t)row * 768;
    float* y = Y + (size_t)row * 768;
    int tid = threadIdx.x;
    __shared__ float rs[4], rss[4];
    float v0 = x[tid], v1 = x[tid + 256], v2 = x[tid + 512];
    float s = v0 + v1 + v2;
    float ss = v0 * v0 + v1 * v1 + v2 * v2;
    for (int off = 32; off; off >>= 1) {
        s  += __shfl_xor(s, off, 64);
        ss += __shfl_xor(ss, off, 64);
    }
    if ((tid & 63) == 0) { rs[tid >> 6] = s; rss[tid >> 6] = ss; }
    __syncthreads();
    s  = rs[0] + rs[1] + rs[2] + rs[3];
    ss = rss[0] + rss[1] + rss[2] + rss[3];
    float mu  = s * (1.f / 768.f);
    float var = ss * (1.f / 768.f) - mu * mu;
    float inv = rsqrtf(var + 1e-6f);
    y[tid]       = (v0 - mu) * inv * g[tid]       + b[tid];
    y[tid + 256] = (v1 - mu) * inv * g[tid + 256] + b[tid + 256];
    y[tid + 512] = (v2 - mu) * inv * g[tid + 512] + b[tid + 512];
}

// ---------------- fp32 tiled GEMM: C[, op] = f(A@B + bias) (+R) -------------
// OP: 0 = store, 1 = exact gelu, 2 = residual add (R may alias C)
template<int OP>
__global__ __launch_bounds__(256)
void gemm_k(const float* __restrict__ A, const float* __restrict__ Bm,
            const float* __restrict__ bias, const float* R, float* C,
            int M, int N, int K)
{
    __shared__ float As[16][132];
    __shared__ float Bs[16][132];
    int bn = blockIdx.x * 128;
    int bm = blockIdx.y * 128;
    int tid = threadIdx.x;
    int tx = tid & 15, ty = tid >> 4;
    int arow = tid >> 2, acol = (tid & 3) * 4;
    int brow = tid >> 5, bcol = (tid & 31) * 4;
    float acc[8][8] = {};

    for (int k0 = 0; k0 < K; k0 += 16) {
        #pragma unroll
        for (int h = 0; h < 2; ++h) {
            int r = bm + arow + h * 64;
            float4 v = make_float4(0, 0, 0, 0);
            if (r < M) v = *(const float4*)(A + (size_t)r * K + k0 + acol);
            As[acol + 0][arow + h * 64] = v.x;
            As[acol + 1][arow + h * 64] = v.y;
            As[acol + 2][arow + h * 64] = v.z;
            As[acol + 3][arow + h * 64] = v.w;
        }
        #pragma unroll
        for (int h = 0; h < 2; ++h) {
            int kr = k0 + brow + h * 8;
            *(float4*)&Bs[brow + h * 8][bcol] = *(const float4*)(Bm + (size_t)kr * N + bn + bcol);
        }
        __syncthreads();
        #pragma unroll
        for (int kk = 0; kk < 16; ++kk) {
            float a[8], bfr[8];
            float4 a0 = *(const float4*)&As[kk][ty * 8];
            float4 a1 = *(const float4*)&As[kk][ty * 8 + 4];
            float4 b0 = *(const float4*)&Bs[kk][tx * 8];
            float4 b1 = *(const float4*)&Bs[kk][tx * 8 + 4];
            a[0]=a0.x; a[1]=a0.y; a[2]=a0.z; a[3]=a0.w;
            a[4]=a1.x; a[5]=a1.y; a[6]=a1.z; a[7]=a1.w;
            bfr[0]=b0.x; bfr[1]=b0.y; bfr[2]=b0.z; bfr[3]=b0.w;
            bfr[4]=b1.x; bfr[5]=b1.y; bfr[6]=b1.z; bfr[7]=b1.w;
            #pragma unroll
            for (int i = 0; i < 8; ++i)
                #pragma unroll
                for (int j = 0; j < 8; ++j)
                    acc[i][j] = fmaf(a[i], bfr[j], acc[i][j]);
        }
        __syncthreads();
    }
    #pragma unroll
    for (int i = 0; i < 8; ++i) {
        int r = bm + ty * 8 + i;
        if (r >= M) continue;
        #pragma unroll
        for (int j = 0; j < 8; ++j) {
            int c = bn + tx * 8 + j;
            float v = acc[i][j] + bias[c];
            if (OP == 1) v = 0.5f * v * (1.f + erff(v * 0.70710678118654752f));
            if (OP == 2) v += R[(size_t)r * N + c];
            C[(size_t)r * N + c] = v;
        }
    }
}

// ---------------- flash attention: 16 q-rows/block, 64-key chunks -----------
__global__ __launch_bounds__(256)
void attn_k(const float* __restrict__ QKV, float* __restrict__ O)
{
    const int T = 577;
    int img = blockIdx.z, head = blockIdx.y;
    int q0 = blockIdx.x * 16;
    const float* base = QKV + (size_t)img * T * 2304;
    __shared__ float Ks[64][68];
    __shared__ float Vs[64][68];
    __shared__ float Ps[16][68];
    int tid = threadIdx.x;
    int qi = tid >> 4, g = tid & 15;
    int tok = q0 + qi;
    float4 qreg[16];
    if (tok < T) {
        const float* qp = base + (size_t)tok * 2304 + head * 64;
        #pragma unroll
        for (int t = 0; t < 16; ++t) {
            float4 v = *(const float4*)(qp + t * 4);
            qreg[t] = make_float4(v.x * 0.125f, v.y * 0.125f, v.z * 0.125f, v.w * 0.125f);
        }
    } else {
        #pragma unroll
        for (int t = 0; t < 16; ++t) qreg[t] = make_float4(0, 0, 0, 0);
    }
    float m = -1e30f, l = 0.f;
    float4 o = make_float4(0, 0, 0, 0);
    for (int c0 = 0; c0 < T; c0 += 64) {
        int nk = min(64, T - c0);
        #pragma unroll
        for (int h = 0; h < 4; ++h) {
            int lin = tid + 256 * h;
            int r = lin >> 4, c = (lin & 15) * 4;
            float4 kv = make_float4(0, 0, 0, 0), vv = make_float4(0, 0, 0, 0);
            if (r < nk) {
                const float* kp = base + (size_t)(c0 + r) * 2304 + 768 + head * 64 + c;
                kv = *(const float4*)kp;
                vv = *(const float4*)(kp + 768);
            }
            *(float4*)&Ks[r][c] = kv;
            *(float4*)&Vs[r][c] = vv;
        }
        __syncthreads();
        float s[4];
        #pragma unroll
        for (int j = 0; j < 4; ++j) {
            int kj = g + 16 * j;
            float acc = 0.f;
            #pragma unroll
            for (int t = 0; t < 16; ++t) {
                float4 k4 = *(const float4*)&Ks[kj][t * 4];
                acc = fmaf(qreg[t].x, k4.x, acc);
                acc = fmaf(qreg[t].y, k4.y, acc);
                acc = fmaf(qreg[t].z, k4.z, acc);
                acc = fmaf(qreg[t].w, k4.w, acc);
            }
            s[j] = (kj < nk) ? acc : -1e30f;
        }
        float mc = fmaxf(fmaxf(s[0], s[1]), fmaxf(s[2], s[3]));
        for (int off = 8; off; off >>= 1) mc = fmaxf(mc, __shfl_xor(mc, off, 16));
        float mnew = fmaxf(m, mc);
        float alpha = __expf(m - mnew);
        float p[4];
        float rsum = 0.f;
        #pragma unroll
        for (int j = 0; j < 4; ++j) { p[j] = __expf(s[j] - mnew); rsum += p[j]; }
        for (int off = 8; off; off >>= 1) rsum += __shfl_xor(rsum, off, 16);
        m = mnew; l = l * alpha + rsum;
        o.x *= alpha; o.y *= alpha; o.z *= alpha; o.w *= alpha;
        #pragma unroll
        for (int j = 0; j < 4; ++j) Ps[qi][g + 16 * j] = p[j];
        __syncthreads();
        #pragma unroll 8
        for (int kj = 0; kj < 64; ++kj) {
            float pv = Ps[qi][kj];
            float4 v4 = *(const float4*)&Vs[kj][g * 4];
            o.x = fmaf(pv, v4.x, o.x);
            o.y = fmaf(pv, v4.y, o.y);
            o.z = fmaf(pv, v4.z, o.z);
            o.w = fmaf(pv, v4.w, o.w);
        }
        __syncthreads();
    }
    if (tok < T) {
        float inv = 1.f / l;
        *(float4*)(O + (size_t)img * T * 768 + (size_t)tok * 768 + head * 64 + g * 4) =
            make_float4(o.x * inv, o.y * inv, o.z * inv, o.w * inv);
    }
}

// ---------------- final LN(cls) + cosine loss -------------------------------
__global__ __launch_bounds__(256)
void final_k(const float* __restrict__ X, const float* __restrict__ g,
             const float* __restrict__ b, float* __restrict__ out)
{
    __shared__ float F[4][768];
    __shared__ float rs[4], rss[4];
    __shared__ float rd[4], rna[4], rnb[4];
    __shared__ float cosv[2];
    int tid = threadIdx.x;
    for (int rr = 0; rr < 4; ++rr) {
        const float* x = X + (size_t)rr * 577 * 768;
        float v0 = x[tid], v1 = x[tid + 256], v2 = x[tid + 512];
        float s = v0 + v1 + v2;
        float ss = v0 * v0 + v1 * v1 + v2 * v2;
        for (int off = 32; off; off >>= 1) {
            s  += __shfl_xor(s, off, 64);
            ss += __shfl_xor(ss, off, 64);
        }
        if ((tid & 63) == 0) { rs[tid >> 6] = s; rss[tid >> 6] = ss; }
        __syncthreads();
        s  = rs[0] + rs[1] + rs[2] + rs[3];
        ss = rss[0] + rss[1] + rss[2] + rss[3];
        float mu  = s * (1.f / 768.f);
        float var = ss * (1.f / 768.f) - mu * mu;
        float inv = rsqrtf(var + 1e-6f);
        F[rr][tid]       = (v0 - mu) * inv * g[tid]       + b[tid];
        F[rr][tid + 256] = (v1 - mu) * inv * g[tid + 256] + b[tid + 256];
        F[rr][tid + 512] = (v2 - mu) * inv * g[tid + 512] + b[tid + 512];
        __syncthreads();
    }
    for (int bb = 0; bb < 2; ++bb) {
        float d = 0.f, na = 0.f, nb = 0.f;
        for (int u = tid; u < 768; u += 256) {
            float fa = F[bb][u], fb = F[bb + 2][u];
            d += fa * fb; na += fa * fa; nb += fb * fb;
        }
        for (int off = 32; off; off >>= 1) {
            d  += __shfl_xor(d, off, 64);
            na += __shfl_xor(na, off, 64);
            nb += __shfl_xor(nb, off, 64);
        }
        if ((tid & 63) == 0) { rd[tid >> 6] = d; rna[tid >> 6] = na; rnb[tid >> 6] = nb; }
        __syncthreads();
        if (tid == 0) {
            float D  = rd[0] + rd[1] + rd[2] + rd[3];
            float NA = sqrtf(rna[0] + rna[1] + rna[2] + rna[3]);
            float NB = sqrtf(rnb[0] + rnb[1] + rnb[2] + rnb[3]);
            cosv[bb] = D / (fmaxf(NA, 1e-8f) * fmaxf(NB, 1e-8f));
        }
        __syncthreads();
    }
    if (tid == 0) out[0] = 1.f - 0.5f * (cosv[0] + cosv[1]);
}

// ---------------- host orchestration ----------------------------------------
extern "C" void kernel_launch(void* const* d_in, const int* in_sizes, int n_in,
                              void* d_out, int out_size, void* d_ws, size_t ws_size,
                              hipStream_t stream)
{
    const float* logits  = (const float*)d_in[0];
    const int*   truem   = (const int*)d_in[1];
    const float* patch_w = (const float*)d_in[2];
    const float* patch_b = (const float*)d_in[3];
    const float* cls_tok = (const float*)d_in[4];
    const float* pos_emb = (const float*)d_in[5];
    const float* ln1_g   = (const float*)d_in[6];
    const float* ln1_b   = (const float*)d_in[7];
    const float* qkv_w   = (const float*)d_in[8];
    const float* qkv_b   = (const float*)d_in[9];
    const float* proj_w  = (const float*)d_in[10];
    const float* proj_b  = (const float*)d_in[11];
    const float* ln2_g   = (const float*)d_in[12];
    const float* ln2_b   = (const float*)d_in[13];
    const float* fc1_w   = (const float*)d_in[14];
    const float* fc1_b   = (const float*)d_in[15];
    const float* fc2_w   = (const float*)d_in[16];
    const float* fc2_b   = (const float*)d_in[17];
    const float* norm_g  = (const float*)d_in[18];
    const float* norm_b  = (const float*)d_in[19];

    float* ws = (float*)d_ws;
    const size_t NX = 1772544;            // 4*577*768
    float* X   = ws;
    float* H   = ws + NX;
    float* O   = ws + 2 * NX;
    float* SCR = ws + 3 * NX;             // 7,090,176 floats of shared scratch
    // EDT/patch phase layout within SCR (sdm reuses O):
    float* g2o  = SCR;
    float* g2z  = SCR + 589824;
    float* pvec = SCR + 1179648;
    float* Weff = SCR + 1769472;
    float* tokb = SCR + 1966080;
    float* sdm  = O;
    // layer-loop layout within SCR:
    float* QKV = SCR;                     // 4*577*2304
    float* MID = SCR;                     // 4*577*3072

    edt_rows_k<<<1536, 64, 0, stream>>>(logits, truem, g2o, g2z);
    edt_cols_k<<<dim3(48, 4), 256, 0, stream>>>(g2o, g2z, sdm);
    weff_k<<<768, 256, 0, stream>>>(patch_w, Weff);
    pvec_k<<<2304, 256, 0, stream>>>(sdm, pvec);
    gemm_k<0><<<dim3(6, 18), 256, 0, stream>>>(pvec, Weff, patch_b, nullptr, tokb,
                                               2304, 768, 256);
    addpos_k<<<6924, 256, 0, stream>>>(tokb, cls_tok, pos_emb, X);

    for (int l = 0; l < 12; ++l) {
        ln_k<<<2308, 256, 0, stream>>>(X, ln1_g + l * 768, ln1_b + l * 768, H);
        gemm_k<0><<<dim3(18, 19), 256, 0, stream>>>(H, qkv_w + (size_t)l * 768 * 2304,
                                                    qkv_b + l * 2304, nullptr, QKV,
                                                    2308, 2304, 768);
        attn_k<<<dim3(37, 12, 4), 256, 0, stream>>>(QKV, O);
        gemm_k<2><<<dim3(6, 19), 256, 0, stream>>>(O, proj_w + (size_t)l * 768 * 768,
                                                   proj_b + l * 768, X, X,
                                                   2308, 768, 768);
        ln_k<<<2308, 256, 0, stream>>>(X, ln2_g + l * 768, ln2_b + l * 768, H);
        gemm_k<1><<<dim3(24, 19), 256, 0, stream>>>(H, fc1_w + (size_t)l * 768 * 3072,
                                                    fc1_b + l * 3072, nullptr, MID,
                                                    2308, 3072, 768);
        gemm_k<2><<<dim3(6, 19), 256, 0, stream>>>(MID, fc2_w + (size_t)l * 3072 * 768,
                                                   fc2_b + l * 768, X, X,
                                                   2308, 768, 3072);
    }
    final_k<<<1, 256, 0, stream>>>(X, norm_g, norm_b, (float*)d_out);
}

// Round 2
// 8222.710 us; speedup vs baseline: 1.5434x; 1.5434x over previous
//
#include <hip/hip_runtime.h>
#include <hip/hip_bf16.h>
#include <math.h>

#define BIGF 1e4f

typedef __attribute__((ext_vector_type(8))) short bf16x8;
typedef __attribute__((ext_vector_type(4))) float f32x4;

__device__ __forceinline__ unsigned short f2bf_rne(float v) {
    unsigned u = __float_as_uint(v);
    return (unsigned short)((u + 0x7FFFu + ((u >> 16) & 1u)) >> 16);
}
__device__ __forceinline__ void split_bf16(float v, unsigned short& h, unsigned short& l) {
    unsigned u = __float_as_uint(v);
    unsigned hr = (u + 0x7FFFu + ((u >> 16) & 1u)) >> 16;
    h = (unsigned short)hr;
    float hf = __uint_as_float(hr << 16);
    l = f2bf_rne(v - hf);
}

// ---------------- EDT row pass: per-row 1D nearest distance (ones & zeros) --
__global__ __launch_bounds__(64)
void edt_rows_k(const float* __restrict__ logits, const int* __restrict__ truem,
                float* __restrict__ g2o, float* __restrict__ g2z)
{
    int blk = blockIdx.x;
    int a = blk / 384, row = blk % 384;
    int lane = threadIdx.x;
    int j0 = lane * 6;
    float mk[6];
    if (a < 2) {
        const float* l0 = logits + (size_t)a * 2 * 147456 + (size_t)row * 384;
        const float* l1 = l0 + 147456;
        #pragma unroll
        for (int u = 0; u < 6; ++u) mk[u] = (l1[j0+u] > l0[j0+u]) ? 1.f : 0.f;
    } else {
        const int* t = truem + (size_t)(a - 2) * 147456 + (size_t)row * 384;
        #pragma unroll
        for (int u = 0; u < 6; ++u) mk[u] = (t[j0+u] != 0) ? 1.f : 0.f;
    }
    float lo[6], lz[6], ro[6], rz[6];
    float run_lo = -BIGF, run_lz = -BIGF;
    #pragma unroll
    for (int u = 0; u < 6; ++u) {
        float jf = (float)(j0 + u);
        if (mk[u] > 0.5f) run_lo = jf; else run_lz = jf;
        lo[u] = run_lo; lz[u] = run_lz;
    }
    float inc_o = run_lo, inc_z = run_lz;
    for (int off = 1; off < 64; off <<= 1) {
        float to = __shfl_up(inc_o, off), tz = __shfl_up(inc_z, off);
        if (lane >= off) { inc_o = fmaxf(inc_o, to); inc_z = fmaxf(inc_z, tz); }
    }
    float ex_o = __shfl_up(inc_o, 1); if (lane == 0) ex_o = -BIGF;
    float ex_z = __shfl_up(inc_z, 1); if (lane == 0) ex_z = -BIGF;

    float run_ro = BIGF, run_rz = BIGF;
    #pragma unroll
    for (int u = 5; u >= 0; --u) {
        float jf = (float)(j0 + u);
        if (mk[u] > 0.5f) run_ro = jf; else run_rz = jf;
        ro[u] = run_ro; rz[u] = run_rz;
    }
    float in2_o = run_ro, in2_z = run_rz;
    for (int off = 1; off < 64; off <<= 1) {
        float to = __shfl_down(in2_o, off), tz = __shfl_down(in2_z, off);
        if (lane + off < 64) { in2_o = fminf(in2_o, to); in2_z = fminf(in2_z, tz); }
    }
    float sx_o = __shfl_down(in2_o, 1); if (lane == 63) sx_o = BIGF;
    float sx_z = __shfl_down(in2_z, 1); if (lane == 63) sx_z = BIGF;

    size_t ob = (size_t)a * 147456 + (size_t)row * 384;
    #pragma unroll
    for (int u = 0; u < 6; ++u) {
        float jf = (float)(j0 + u);
        float dlo = jf - fmaxf(lo[u], ex_o);
        float dro = fminf(ro[u], sx_o) - jf;
        float go = fminf(fminf(dlo, dro), BIGF);
        float dlz = jf - fmaxf(lz[u], ex_z);
        float drz = fminf(rz[u], sx_z) - jf;
        float gz = fminf(fminf(dlz, drz), BIGF);
        g2o[ob + j0 + u] = go * go;
        g2z[ob + j0 + u] = gz * gz;
    }
}

// ---------------- EDT column pass: min-plus over rows, emit signed distance --
__global__ __launch_bounds__(256)
void edt_cols_k(const float* __restrict__ g2o, const float* __restrict__ g2z,
                float* __restrict__ sdm)
{
    int a = blockIdx.y;
    int w0 = blockIdx.x * 8;
    __shared__ float so[384][8];
    __shared__ float sz[384][8];
    int tid = threadIdx.x;
    for (int h = 0; h < 12; ++h) {
        int lin = tid + 256 * h;           // 0..3071
        int ip = lin >> 3, ww = lin & 7;
        so[ip][ww] = g2o[(size_t)a * 147456 + (size_t)ip * 384 + w0 + ww];
        sz[ip][ww] = g2z[(size_t)a * 147456 + (size_t)ip * 384 + w0 + ww];
    }
    __syncthreads();
    int w = tid & 7, ib = tid >> 3;        // ib 0..31
    float vo[12], vz[12];
    #pragma unroll
    for (int r = 0; r < 12; ++r) { vo[r] = 3.4e38f; vz[r] = 3.4e38f; }
    for (int ip = 0; ip < 384; ++ip) {
        float go = so[ip][w], gz = sz[ip][w];
        #pragma unroll
        for (int r = 0; r < 12; ++r) {
            float d = (float)(ib + 32 * r - ip);
            float dd = d * d;
            vo[r] = fminf(vo[r], dd + go);
            vz[r] = fminf(vz[r], dd + gz);
        }
    }
    #pragma unroll
    for (int r = 0; r < 12; ++r) {
        sdm[(size_t)a * 147456 + (size_t)(ib + 32 * r) * 384 + w0 + w] =
            sqrtf(vo[r]) - sqrtf(vz[r]);
    }
}

// ---------------- channel-reduced patch weight ------------------------------
__global__ void weff_k(const float* __restrict__ pw, float* __restrict__ W)
{
    int i = blockIdx.x * 256 + threadIdx.x;
    if (i < 196608) W[i] = pw[i] + pw[i + 196608] + pw[i + 393216];
}

// ---------------- gather patch vectors [4*576, 256] -------------------------
__global__ void pvec_k(const float* __restrict__ sdm, float* __restrict__ pvec)
{
    int idx = blockIdx.x * 256 + threadIdx.x;   // 589824 total
    int cc = idx & 15, r = (idx >> 4) & 15, p = idx >> 8;
    int px = p % 24, py = (p / 24) % 24, aa = p / 576;
    pvec[idx] = sdm[(size_t)aa * 147456 + (size_t)(py * 16 + r) * 384 + px * 16 + cc];
}

// ---------------- cls + pos assembly ---------------------------------------
__global__ void addpos_k(const float* __restrict__ tok, const float* __restrict__ cls,
                         const float* __restrict__ pos, float* __restrict__ X)
{
    int idx = blockIdx.x * 256 + threadIdx.x;
    if (idx >= 1772544) return;
    int d = idx % 768;
    int t = (idx / 768) % 577;
    int img = idx / (768 * 577);
    float v;
    if (t == 0) v = cls[d] + pos[d];
    else v = tok[((size_t)img * 576 + (t - 1)) * 768 + d] + pos[(size_t)t * 768 + d];
    X[idx] = v;
}

// ---------------- LayerNorm (rows of 768) -----------------------------------
__global__ __launch_bounds__(256)
void ln_k(const float* __restrict__ X, const float* __restrict__ g,
          const float* __restrict__ b, float* __restrict__ Y)
{
    int row = blockIdx.x;
    const float* x = X + (size_t)row * 768;
    float* y = Y + (size_t)row * 768;
    int tid = threadIdx.x;
    __shared__ float rs[4], rss[4];
    float v0 = x[tid], v1 = x[tid + 256], v2 = x[tid + 512];
    float s = v0 + v1 + v2;
    float ss = v0 * v0 + v1 * v1 + v2 * v2;
    for (int off = 32; off; off >>= 1) {
        s  += __shfl_xor(s, off, 64);
        ss += __shfl_xor(ss, off, 64);
    }
    if ((tid & 63) == 0) { rs[tid >> 6] = s; rss[tid >> 6] = ss; }
    __syncthreads();
    s  = rs[0] + rs[1] + rs[2] + rs[3];
    ss = rss[0] + rss[1] + rss[2] + rss[3];
    float mu  = s * (1.f / 768.f);
    float var = ss * (1.f / 768.f) - mu * mu;
    float inv = rsqrtf(var + 1e-6f);
    y[tid]       = (v0 - mu) * inv * g[tid]       + b[tid];
    y[tid + 256] = (v1 - mu) * inv * g[tid + 256] + b[tid + 256];
    y[tid + 512] = (v2 - mu) * inv * g[tid + 512] + b[tid + 512];
}

// ---------------- split-bf16 MFMA GEMM: C = f(A@B + bias) (+R) --------------
// A [M,K] fp32 row-major, B [K,N] fp32 row-major. 128x128 block tile, 4 waves,
// each wave 64x64 via 4x4 grid of 16x16x32 bf16 MFMAs. Each fp32 operand is
// split a = hi + lo (bf16 each); D ~= hi*hi + hi*lo + lo*hi (~17-bit mantissa).
// OP: 0 = store, 1 = exact gelu, 2 = residual add (R may alias C)
// Requires: N % 128 == 0, K % 32 == 0. M arbitrary (guarded).
template<int OP>
__global__ __launch_bounds__(256)
void gemm_mfma_k(const float* __restrict__ A, const float* __restrict__ Bm,
                 const float* __restrict__ bias, const float* R, float* C,
                 int M, int N, int K)
{
    __shared__ unsigned short Ah[128 * 40];
    __shared__ unsigned short Al[128 * 40];
    __shared__ unsigned short Bh[128 * 40];
    __shared__ unsigned short Bl[128 * 40];

    int tid = threadIdx.x;
    int bn = blockIdx.x * 128;
    int bm = blockIdx.y * 128;

    int lane = tid & 63, wave = tid >> 6;
    int ln = lane & 15, quad = lane >> 4;
    int wm = (wave >> 1) * 64, wn = (wave & 1) * 64;

    // staging maps
    int a_kq = (tid & 7) * 4;      // k offset (fp32 elems)
    int a_m0 = tid >> 3;           // 0..31, +32*h
    int b_n  = tid & 127;
    int b_kb = (tid >> 7) * 16;

    f32x4 acc[4][4] = {};

    for (int k0 = 0; k0 < K; k0 += 32) {
        // ---- stage A tile [128 m][32 k] with split conversion
        #pragma unroll
        for (int h = 0; h < 4; ++h) {
            int m = a_m0 + 32 * h;
            int r = bm + m;
            float4 v = make_float4(0.f, 0.f, 0.f, 0.f);
            if (r < M) v = *(const float4*)(A + (size_t)r * K + k0 + a_kq);
            unsigned short h0, h1, h2, h3, l0, l1, l2, l3;
            split_bf16(v.x, h0, l0); split_bf16(v.y, h1, l1);
            split_bf16(v.z, h2, l2); split_bf16(v.w, h3, l3);
            *(ushort4*)&Ah[m * 40 + a_kq] = make_ushort4(h0, h1, h2, h3);
            *(ushort4*)&Al[m * 40 + a_kq] = make_ushort4(l0, l1, l2, l3);
        }
        // ---- stage B tile transposed: Bt[128 n][32 k]
        {
            const float* bp = Bm + (size_t)(k0 + b_kb) * N + bn + b_n;
            #pragma unroll
            for (int g = 0; g < 2; ++g) {
                unsigned short hh[8], ll[8];
                #pragma unroll
                for (int j = 0; j < 8; ++j) {
                    float v = bp[(size_t)(g * 8 + j) * N];
                    split_bf16(v, hh[j], ll[j]);
                }
                *(ushort4*)&Bh[b_n * 40 + b_kb + g * 8]     = make_ushort4(hh[0], hh[1], hh[2], hh[3]);
                *(ushort4*)&Bh[b_n * 40 + b_kb + g * 8 + 4] = make_ushort4(hh[4], hh[5], hh[6], hh[7]);
                *(ushort4*)&Bl[b_n * 40 + b_kb + g * 8]     = make_ushort4(ll[0], ll[1], ll[2], ll[3]);
                *(ushort4*)&Bl[b_n * 40 + b_kb + g * 8 + 4] = make_ushort4(ll[4], ll[5], ll[6], ll[7]);
            }
        }
        __syncthreads();

        // ---- MFMA compute
        bf16x8 bh[4], bl[4];
        #pragma unroll
        for (int nt = 0; nt < 4; ++nt) {
            bh[nt] = *(const bf16x8*)&Bh[(wn + nt * 16 + ln) * 40 + quad * 8];
            bl[nt] = *(const bf16x8*)&Bl[(wn + nt * 16 + ln) * 40 + quad * 8];
        }
        #pragma unroll
        for (int mt = 0; mt < 4; ++mt) {
            bf16x8 ah = *(const bf16x8*)&Ah[(wm + mt * 16 + ln) * 40 + quad * 8];
            bf16x8 al = *(const bf16x8*)&Al[(wm + mt * 16 + ln) * 40 + quad * 8];
            #pragma unroll
            for (int nt = 0; nt < 4; ++nt) {
                acc[mt][nt] = __builtin_amdgcn_mfma_f32_16x16x32_bf16(ah, bh[nt], acc[mt][nt], 0, 0, 0);
                acc[mt][nt] = __builtin_amdgcn_mfma_f32_16x16x32_bf16(ah, bl[nt], acc[mt][nt], 0, 0, 0);
                acc[mt][nt] = __builtin_amdgcn_mfma_f32_16x16x32_bf16(al, bh[nt], acc[mt][nt], 0, 0, 0);
            }
        }
        __syncthreads();
    }

    // ---- epilogue: D row = quad*4 + reg, col = ln
    #pragma unroll
    for (int mt = 0; mt < 4; ++mt) {
        #pragma unroll
        for (int i = 0; i < 4; ++i) {
            int r = bm + wm + mt * 16 + quad * 4 + i;
            if (r >= M) continue;
            #pragma unroll
            for (int nt = 0; nt < 4; ++nt) {
                int c = bn + wn + nt * 16 + ln;
                float v = acc[mt][nt][i] + bias[c];
                if (OP == 1) v = 0.5f * v * (1.f + erff(v * 0.70710678118654752f));
                if (OP == 2) v += R[(size_t)r * N + c];
                C[(size_t)r * N + c] = v;
            }
        }
    }
}

// ---------------- flash attention: 16 q-rows/block, 64-key chunks -----------
__global__ __launch_bounds__(256)
void attn_k(const float* __restrict__ QKV, float* __restrict__ O)
{
    const int T = 577;
    int img = blockIdx.z, head = blockIdx.y;
    int q0 = blockIdx.x * 16;
    const float* base = QKV + (size_t)img * T * 2304;
    __shared__ float Ks[64][68];
    __shared__ float Vs[64][68];
    __shared__ float Ps[16][68];
    int tid = threadIdx.x;
    int qi = tid >> 4, g = tid & 15;
    int tok = q0 + qi;
    float4 qreg[16];
    if (tok < T) {
        const float* qp = base + (size_t)tok * 2304 + head * 64;
        #pragma unroll
        for (int t = 0; t < 16; ++t) {
            float4 v = *(const float4*)(qp + t * 4);
            qreg[t] = make_float4(v.x * 0.125f, v.y * 0.125f, v.z * 0.125f, v.w * 0.125f);
        }
    } else {
        #pragma unroll
        for (int t = 0; t < 16; ++t) qreg[t] = make_float4(0, 0, 0, 0);
    }
    float m = -1e30f, l = 0.f;
    float4 o = make_float4(0, 0, 0, 0);
    for (int c0 = 0; c0 < T; c0 += 64) {
        int nk = min(64, T - c0);
        #pragma unroll
        for (int h = 0; h < 4; ++h) {
            int lin = tid + 256 * h;
            int r = lin >> 4, c = (lin & 15) * 4;
            float4 kv = make_float4(0, 0, 0, 0), vv = make_float4(0, 0, 0, 0);
            if (r < nk) {
                const float* kp = base + (size_t)(c0 + r) * 2304 + 768 + head * 64 + c;
                kv = *(const float4*)kp;
                vv = *(const float4*)(kp + 768);
            }
            *(float4*)&Ks[r][c] = kv;
            *(float4*)&Vs[r][c] = vv;
        }
        __syncthreads();
        float s[4];
        #pragma unroll
        for (int j = 0; j < 4; ++j) {
            int kj = g + 16 * j;
            float acc = 0.f;
            #pragma unroll
            for (int t = 0; t < 16; ++t) {
                float4 k4 = *(const float4*)&Ks[kj][t * 4];
                acc = fmaf(qreg[t].x, k4.x, acc);
                acc = fmaf(qreg[t].y, k4.y, acc);
                acc = fmaf(qreg[t].z, k4.z, acc);
                acc = fmaf(qreg[t].w, k4.w, acc);
            }
            s[j] = (kj < nk) ? acc : -1e30f;
        }
        float mc = fmaxf(fmaxf(s[0], s[1]), fmaxf(s[2], s[3]));
        for (int off = 8; off; off >>= 1) mc = fmaxf(mc, __shfl_xor(mc, off, 16));
        float mnew = fmaxf(m, mc);
        float alpha = __expf(m - mnew);
        float p[4];
        float rsum = 0.f;
        #pragma unroll
        for (int j = 0; j < 4; ++j) { p[j] = __expf(s[j] - mnew); rsum += p[j]; }
        for (int off = 8; off; off >>= 1) rsum += __shfl_xor(rsum, off, 16);
        m = mnew; l = l * alpha + rsum;
        o.x *= alpha; o.y *= alpha; o.z *= alpha; o.w *= alpha;
        #pragma unroll
        for (int j = 0; j < 4; ++j) Ps[qi][g + 16 * j] = p[j];
        __syncthreads();
        #pragma unroll 8
        for (int kj = 0; kj < 64; ++kj) {
            float pv = Ps[qi][kj];
            float4 v4 = *(const float4*)&Vs[kj][g * 4];
            o.x = fmaf(pv, v4.x, o.x);
            o.y = fmaf(pv, v4.y, o.y);
            o.z = fmaf(pv, v4.z, o.z);
            o.w = fmaf(pv, v4.w, o.w);
        }
        __syncthreads();
    }
    if (tok < T) {
        float inv = 1.f / l;
        *(float4*)(O + (size_t)img * T * 768 + (size_t)tok * 768 + head * 64 + g * 4) =
            make_float4(o.x * inv, o.y * inv, o.z * inv, o.w * inv);
    }
}

// ---------------- final LN(cls) + cosine loss -------------------------------
__global__ __launch_bounds__(256)
void final_k(const float* __restrict__ X, const float* __restrict__ g,
             const float* __restrict__ b, float* __restrict__ out)
{
    __shared__ float F[4][768];
    __shared__ float rs[4], rss[4];
    __shared__ float rd[4], rna[4], rnb[4];
    __shared__ float cosv[2];
    int tid = threadIdx.x;
    for (int rr = 0; rr < 4; ++rr) {
        const float* x = X + (size_t)rr * 577 * 768;
        float v0 = x[tid], v1 = x[tid + 256], v2 = x[tid + 512];
        float s = v0 + v1 + v2;
        float ss = v0 * v0 + v1 * v1 + v2 * v2;
        for (int off = 32; off; off >>= 1) {
            s  += __shfl_xor(s, off, 64);
            ss += __shfl_xor(ss, off, 64);
        }
        if ((tid & 63) == 0) { rs[tid >> 6] = s; rss[tid >> 6] = ss; }
        __syncthreads();
        s  = rs[0] + rs[1] + rs[2] + rs[3];
        ss = rss[0] + rss[1] + rss[2] + rss[3];
        float mu  = s * (1.f / 768.f);
        float var = ss * (1.f / 768.f) - mu * mu;
        float inv = rsqrtf(var + 1e-6f);
        F[rr][tid]       = (v0 - mu) * inv * g[tid]       + b[tid];
        F[rr][tid + 256] = (v1 - mu) * inv * g[tid + 256] + b[tid + 256];
        F[rr][tid + 512] = (v2 - mu) * inv * g[tid + 512] + b[tid + 512];
        __syncthreads();
    }
    for (int bb = 0; bb < 2; ++bb) {
        float d = 0.f, na = 0.f, nb = 0.f;
        for (int u = tid; u < 768; u += 256) {
            float fa = F[bb][u], fb = F[bb + 2][u];
            d += fa * fb; na += fa * fa; nb += fb * fb;
        }
        for (int off = 32; off; off >>= 1) {
            d  += __shfl_xor(d, off, 64);
            na += __shfl_xor(na, off, 64);
            nb += __shfl_xor(nb, off, 64);
        }
        if ((tid & 63) == 0) { rd[tid >> 6] = d; rna[tid >> 6] = na; rnb[tid >> 6] = nb; }
        __syncthreads();
        if (tid == 0) {
            float D  = rd[0] + rd[1] + rd[2] + rd[3];
            float NA = sqrtf(rna[0] + rna[1] + rna[2] + rna[3]);
            float NB = sqrtf(rnb[0] + rnb[1] + rnb[2] + rnb[3]);
            cosv[bb] = D / (fmaxf(NA, 1e-8f) * fmaxf(NB, 1e-8f));
        }
        __syncthreads();
    }
    if (tid == 0) out[0] = 1.f - 0.5f * (cosv[0] + cosv[1]);
}

// ---------------- host orchestration ----------------------------------------
extern "C" void kernel_launch(void* const* d_in, const int* in_sizes, int n_in,
                              void* d_out, int out_size, void* d_ws, size_t ws_size,
                              hipStream_t stream)
{
    const float* logits  = (const float*)d_in[0];
    const int*   truem   = (const int*)d_in[1];
    const float* patch_w = (const float*)d_in[2];
    const float* patch_b = (const float*)d_in[3];
    const float* cls_tok = (const float*)d_in[4];
    const float* pos_emb = (const float*)d_in[5];
    const float* ln1_g   = (const float*)d_in[6];
    const float* ln1_b   = (const float*)d_in[7];
    const float* qkv_w   = (const float*)d_in[8];
    const float* qkv_b   = (const float*)d_in[9];
    const float* proj_w  = (const float*)d_in[10];
    const float* proj_b  = (const float*)d_in[11];
    const float* ln2_g   = (const float*)d_in[12];
    const float* ln2_b   = (const float*)d_in[13];
    const float* fc1_w   = (const float*)d_in[14];
    const float* fc1_b   = (const float*)d_in[15];
    const float* fc2_w   = (const float*)d_in[16];
    const float* fc2_b   = (const float*)d_in[17];
    const float* norm_g  = (const float*)d_in[18];
    const float* norm_b  = (const float*)d_in[19];

    float* ws = (float*)d_ws;
    const size_t NX = 1772544;            // 4*577*768
    float* X   = ws;
    float* H   = ws + NX;
    float* O   = ws + 2 * NX;
    float* SCR = ws + 3 * NX;             // shared scratch
    // EDT/patch phase layout within SCR (sdm reuses O):
    float* g2o  = SCR;
    float* g2z  = SCR + 589824;
    float* pvec = SCR + 1179648;
    float* Weff = SCR + 1769472;
    float* tokb = SCR + 1966080;
    float* sdm  = O;
    // layer-loop layout within SCR:
    float* QKV = SCR;                     // 4*577*2304
    float* MID = SCR;                     // 4*577*3072

    edt_rows_k<<<1536, 64, 0, stream>>>(logits, truem, g2o, g2z);
    edt_cols_k<<<dim3(48, 4), 256, 0, stream>>>(g2o, g2z, sdm);
    weff_k<<<768, 256, 0, stream>>>(patch_w, Weff);
    pvec_k<<<2304, 256, 0, stream>>>(sdm, pvec);
    gemm_mfma_k<0><<<dim3(6, 18), 256, 0, stream>>>(pvec, Weff, patch_b, nullptr, tokb,
                                                    2304, 768, 256);
    addpos_k<<<6924, 256, 0, stream>>>(tokb, cls_tok, pos_emb, X);

    for (int l = 0; l < 12; ++l) {
        ln_k<<<2308, 256, 0, stream>>>(X, ln1_g + l * 768, ln1_b + l * 768, H);
        gemm_mfma_k<0><<<dim3(18, 19), 256, 0, stream>>>(H, qkv_w + (size_t)l * 768 * 2304,
                                                         qkv_b + l * 2304, nullptr, QKV,
                                                         2308, 2304, 768);
        attn_k<<<dim3(37, 12, 4), 256, 0, stream>>>(QKV, O);
        gemm_mfma_k<2><<<dim3(6, 19), 256, 0, stream>>>(O, proj_w + (size_t)l * 768 * 768,
                                                        proj_b + l * 768, X, X,
                                                        2308, 768, 768);
        ln_k<<<2308, 256, 0, stream>>>(X, ln2_g + l * 768, ln2_b + l * 768, H);
        gemm_mfma_k<1><<<dim3(24, 19), 256, 0, stream>>>(H, fc1_w + (size_t)l * 768 * 3072,
                                                         fc1_b + l * 3072, nullptr, MID,
                                                         2308, 3072, 768);
        gemm_mfma_k<2><<<dim3(6, 19), 256, 0, stream>>>(MID, fc2_w + (size_t)l * 3072 * 768,
                                                        fc2_b + l * 768, X, X,
                                                        2308, 768, 3072);
    }
    final_k<<<1, 256, 0, stream>>>(X, norm_g, norm_b, (float*)d_out);
}

// Round 3
// 5130.566 us; speedup vs baseline: 2.4736x; 1.6027x over previous
//
#include <hip/hip_runtime.h>
#include <hip/hip_bf16.h>
#include <math.h>

#define BIGF 1e4f

typedef __attribute__((ext_vector_type(8))) short bf16x8;
typedef __attribute__((ext_vector_type(4))) float f32x4;

__device__ __forceinline__ unsigned short f2bf_rne(float v) {
    unsigned u = __float_as_uint(v);
    return (unsigned short)((u + 0x7FFFu + ((u >> 16) & 1u)) >> 16);
}
__device__ __forceinline__ void split_bf16(float v, unsigned short& h, unsigned short& l) {
    unsigned u = __float_as_uint(v);
    unsigned hr = (u + 0x7FFFu + ((u >> 16) & 1u)) >> 16;
    h = (unsigned short)hr;
    float hf = __uint_as_float(hr << 16);
    l = f2bf_rne(v - hf);
}

// async global->LDS, 16B per lane, wave-uniform LDS base + lane*16
__device__ __forceinline__ void gl16(const unsigned short* g, unsigned short* l) {
    __builtin_amdgcn_global_load_lds(
        (const __attribute__((address_space(1))) unsigned int*)g,
        (__attribute__((address_space(3))) unsigned int*)l, 16, 0, 0);
}

// ---------------- EDT row pass ----------------------------------------------
__global__ __launch_bounds__(64)
void edt_rows_k(const float* __restrict__ logits, const int* __restrict__ truem,
                float* __restrict__ g2o, float* __restrict__ g2z)
{
    int blk = blockIdx.x;
    int a = blk / 384, row = blk % 384;
    int lane = threadIdx.x;
    int j0 = lane * 6;
    float mk[6];
    if (a < 2) {
        const float* l0 = logits + (size_t)a * 2 * 147456 + (size_t)row * 384;
        const float* l1 = l0 + 147456;
        #pragma unroll
        for (int u = 0; u < 6; ++u) mk[u] = (l1[j0+u] > l0[j0+u]) ? 1.f : 0.f;
    } else {
        const int* t = truem + (size_t)(a - 2) * 147456 + (size_t)row * 384;
        #pragma unroll
        for (int u = 0; u < 6; ++u) mk[u] = (t[j0+u] != 0) ? 1.f : 0.f;
    }
    float lo[6], lz[6], ro[6], rz[6];
    float run_lo = -BIGF, run_lz = -BIGF;
    #pragma unroll
    for (int u = 0; u < 6; ++u) {
        float jf = (float)(j0 + u);
        if (mk[u] > 0.5f) run_lo = jf; else run_lz = jf;
        lo[u] = run_lo; lz[u] = run_lz;
    }
    float inc_o = run_lo, inc_z = run_lz;
    for (int off = 1; off < 64; off <<= 1) {
        float to = __shfl_up(inc_o, off), tz = __shfl_up(inc_z, off);
        if (lane >= off) { inc_o = fmaxf(inc_o, to); inc_z = fmaxf(inc_z, tz); }
    }
    float ex_o = __shfl_up(inc_o, 1); if (lane == 0) ex_o = -BIGF;
    float ex_z = __shfl_up(inc_z, 1); if (lane == 0) ex_z = -BIGF;

    float run_ro = BIGF, run_rz = BIGF;
    #pragma unroll
    for (int u = 5; u >= 0; --u) {
        float jf = (float)(j0 + u);
        if (mk[u] > 0.5f) run_ro = jf; else run_rz = jf;
        ro[u] = run_ro; rz[u] = run_rz;
    }
    float in2_o = run_ro, in2_z = run_rz;
    for (int off = 1; off < 64; off <<= 1) {
        float to = __shfl_down(in2_o, off), tz = __shfl_down(in2_z, off);
        if (lane + off < 64) { in2_o = fminf(in2_o, to); in2_z = fminf(in2_z, tz); }
    }
    float sx_o = __shfl_down(in2_o, 1); if (lane == 63) sx_o = BIGF;
    float sx_z = __shfl_down(in2_z, 1); if (lane == 63) sx_z = BIGF;

    size_t ob = (size_t)a * 147456 + (size_t)row * 384;
    #pragma unroll
    for (int u = 0; u < 6; ++u) {
        float jf = (float)(j0 + u);
        float dlo = jf - fmaxf(lo[u], ex_o);
        float dro = fminf(ro[u], sx_o) - jf;
        float go = fminf(fminf(dlo, dro), BIGF);
        float dlz = jf - fmaxf(lz[u], ex_z);
        float drz = fminf(rz[u], sx_z) - jf;
        float gz = fminf(fminf(dlz, drz), BIGF);
        g2o[ob + j0 + u] = go * go;
        g2z[ob + j0 + u] = gz * gz;
    }
}

// ---------------- EDT column pass -------------------------------------------
__global__ __launch_bounds__(256)
void edt_cols_k(const float* __restrict__ g2o, const float* __restrict__ g2z,
                float* __restrict__ sdm)
{
    int a = blockIdx.y;
    int w0 = blockIdx.x * 8;
    __shared__ float so[384][8];
    __shared__ float sz[384][8];
    int tid = threadIdx.x;
    for (int h = 0; h < 12; ++h) {
        int lin = tid + 256 * h;
        int ip = lin >> 3, ww = lin & 7;
        so[ip][ww] = g2o[(size_t)a * 147456 + (size_t)ip * 384 + w0 + ww];
        sz[ip][ww] = g2z[(size_t)a * 147456 + (size_t)ip * 384 + w0 + ww];
    }
    __syncthreads();
    int w = tid & 7, ib = tid >> 3;
    float vo[12], vz[12];
    #pragma unroll
    for (int r = 0; r < 12; ++r) { vo[r] = 3.4e38f; vz[r] = 3.4e38f; }
    for (int ip = 0; ip < 384; ++ip) {
        float go = so[ip][w], gz = sz[ip][w];
        #pragma unroll
        for (int r = 0; r < 12; ++r) {
            float d = (float)(ib + 32 * r - ip);
            float dd = d * d;
            vo[r] = fminf(vo[r], dd + go);
            vz[r] = fminf(vz[r], dd + gz);
        }
    }
    #pragma unroll
    for (int r = 0; r < 12; ++r) {
        sdm[(size_t)a * 147456 + (size_t)(ib + 32 * r) * 384 + w0 + w] =
            sqrtf(vo[r]) - sqrtf(vz[r]);
    }
}

// ---------------- channel-reduced patch weight ------------------------------
__global__ void weff_k(const float* __restrict__ pw, float* __restrict__ W)
{
    int i = blockIdx.x * 256 + threadIdx.x;
    if (i < 196608) W[i] = pw[i] + pw[i + 196608] + pw[i + 393216];
}

// ---------------- generic transpose + split: [K,N] f32 -> [N,K] bf16 h/l ----
__global__ __launch_bounds__(256)
void tconv_k(const float* __restrict__ src, unsigned short* __restrict__ dh,
             unsigned short* __restrict__ dl, int K, int N)
{
    __shared__ float tile[32][33];
    int t = blockIdx.x;
    int ntk = K >> 5;
    int tn = t / ntk, tk = t % ntk;
    int tid = threadIdx.x;
    int tx = tid & 31, ty = tid >> 5;
    #pragma unroll
    for (int i = 0; i < 4; ++i) {
        int k = tk * 32 + ty + i * 8;
        tile[ty + i * 8][tx] = src[(size_t)k * N + tn * 32 + tx];
    }
    __syncthreads();
    #pragma unroll
    for (int i = 0; i < 4; ++i) {
        int n = tn * 32 + ty + i * 8;
        float v = tile[tx][ty + i * 8];
        unsigned short h, l;
        split_bf16(v, h, l);
        dh[(size_t)n * K + tk * 32 + tx] = h;
        dl[(size_t)n * K + tk * 32 + tx] = l;
    }
}

// ---------------- fused per-layer weight transpose+split --------------------
__global__ __launch_bounds__(256)
void wconv_layer_k(const float* __restrict__ qkv, const float* __restrict__ proj,
                   const float* __restrict__ fc1, const float* __restrict__ fc2,
                   unsigned short* qkvTh, unsigned short* qkvTl,
                   unsigned short* projTh, unsigned short* projTl,
                   unsigned short* fc1Th, unsigned short* fc1Tl,
                   unsigned short* fc2Th, unsigned short* fc2Tl)
{
    __shared__ float tile[32][33];
    int t = blockIdx.x;
    const float* src; unsigned short *dh, *dl; int K, N, tt;
    if (t < 1728)      { src = qkv;  dh = qkvTh;  dl = qkvTl;  K = 768;  N = 2304; tt = t; }
    else if (t < 2304) { src = proj; dh = projTh; dl = projTl; K = 768;  N = 768;  tt = t - 1728; }
    else if (t < 4608) { src = fc1;  dh = fc1Th;  dl = fc1Tl;  K = 768;  N = 3072; tt = t - 2304; }
    else               { src = fc2;  dh = fc2Th;  dl = fc2Tl;  K = 3072; N = 768;  tt = t - 4608; }
    int ntk = K >> 5;
    int tn = tt / ntk, tk = tt % ntk;
    int tid = threadIdx.x;
    int tx = tid & 31, ty = tid >> 5;
    #pragma unroll
    for (int i = 0; i < 4; ++i) {
        int k = tk * 32 + ty + i * 8;
        tile[ty + i * 8][tx] = src[(size_t)k * N + tn * 32 + tx];
    }
    __syncthreads();
    #pragma unroll
    for (int i = 0; i < 4; ++i) {
        int n = tn * 32 + ty + i * 8;
        float v = tile[tx][ty + i * 8];
        unsigned short h, l;
        split_bf16(v, h, l);
        dh[(size_t)n * K + tk * 32 + tx] = h;
        dl[(size_t)n * K + tk * 32 + tx] = l;
    }
}

// ---------------- gather patch vectors, split -------------------------------
__global__ void pvec_split_k(const float* __restrict__ sdm,
                             unsigned short* __restrict__ ph,
                             unsigned short* __restrict__ pl)
{
    int idx = blockIdx.x * 256 + threadIdx.x;   // 589824 total
    int cc = idx & 15, r = (idx >> 4) & 15, p = idx >> 8;
    int px = p % 24, py = (p / 24) % 24, aa = p / 576;
    float v = sdm[(size_t)aa * 147456 + (size_t)(py * 16 + r) * 384 + px * 16 + cc];
    unsigned short h, l;
    split_bf16(v, h, l);
    ph[idx] = h; pl[idx] = l;
}

// ---------------- cls + pos assembly ---------------------------------------
__global__ void addpos_k(const float* __restrict__ tok, const float* __restrict__ cls,
                         const float* __restrict__ pos, float* __restrict__ X)
{
    int idx = blockIdx.x * 256 + threadIdx.x;
    if (idx >= 1772544) return;
    int d = idx % 768;
    int t = (idx / 768) % 577;
    int img = idx / (768 * 577);
    float v;
    if (t == 0) v = cls[d] + pos[d];
    else v = tok[((size_t)img * 576 + (t - 1)) * 768 + d] + pos[(size_t)t * 768 + d];
    X[idx] = v;
}

// ---------------- LayerNorm -> split bf16 -----------------------------------
__global__ __launch_bounds__(256)
void ln_split_k(const float* __restrict__ X, const float* __restrict__ g,
                const float* __restrict__ b, unsigned short* __restrict__ Yh,
                unsigned short* __restrict__ Yl)
{
    int row = blockIdx.x;
    const float* x = X + (size_t)row * 768;
    int tid = threadIdx.x;
    __shared__ float rs[4], rss[4];
    float v0 = x[tid], v1 = x[tid + 256], v2 = x[tid + 512];
    float s = v0 + v1 + v2;
    float ss = v0 * v0 + v1 * v1 + v2 * v2;
    for (int off = 32; off; off >>= 1) {
        s  += __shfl_xor(s, off, 64);
        ss += __shfl_xor(ss, off, 64);
    }
    if ((tid & 63) == 0) { rs[tid >> 6] = s; rss[tid >> 6] = ss; }
    __syncthreads();
    s  = rs[0] + rs[1] + rs[2] + rs[3];
    ss = rss[0] + rss[1] + rss[2] + rss[3];
    float mu  = s * (1.f / 768.f);
    float var = ss * (1.f / 768.f) - mu * mu;
    float inv = rsqrtf(var + 1e-6f);
    unsigned short h, l;
    float y0 = (v0 - mu) * inv * g[tid]       + b[tid];
    float y1 = (v1 - mu) * inv * g[tid + 256] + b[tid + 256];
    float y2 = (v2 - mu) * inv * g[tid + 512] + b[tid + 512];
    size_t base = (size_t)row * 768;
    split_bf16(y0, h, l); Yh[base + tid]       = h; Yl[base + tid]       = l;
    split_bf16(y1, h, l); Yh[base + tid + 256] = h; Yl[base + tid + 256] = l;
    split_bf16(y2, h, l); Yh[base + tid + 512] = h; Yl[base + tid + 512] = l;
}

// ---------------- split-bf16 MFMA GEMM (m97 structure) ----------------------
// A: Ah/Al [M,K] bf16 row-major (M padded to 128-mult in memory)
// B: Bh/Bl [N,K] bf16 row-major (pre-transposed weights)
// OP: 0 = store fp32 Cf, 1 = gelu -> split bf16 Ch/Cl, 2 = fp32 residual Cf=acc+bias+R
template<int OP>
__global__ __launch_bounds__(256, 2)
void gemm_bt_k(const unsigned short* __restrict__ Ah_g, const unsigned short* __restrict__ Al_g,
               const unsigned short* __restrict__ Bh_g, const unsigned short* __restrict__ Bl_g,
               const float* __restrict__ bias, const float* __restrict__ R,
               float* __restrict__ Cf, unsigned short* __restrict__ Ch,
               unsigned short* __restrict__ Cl, int M, int N, int K)
{
    __shared__ unsigned short Ah[128 * 32];
    __shared__ unsigned short Al[128 * 32];
    __shared__ unsigned short Bh[128 * 32];
    __shared__ unsigned short Bl[128 * 32];

    int tid = threadIdx.x;
    int lane = tid & 63, wave = tid >> 6;
    int bn = blockIdx.x * 128, bm = blockIdx.y * 128;
    int ln = lane & 15, quad = lane >> 4;
    int wm = (wave >> 1) * 64, wn = (wave & 1) * 64;

    // staging: each wave stages rows [wave*32, wave*32+32) of each tile,
    // 16 rows per global_load_lds (64 lanes x 16B = 1KB = 16 rows x 64B)
    int srow = wave * 32 + (lane >> 2);
    int scol = (lane & 3) * 8;
    const unsigned short* pAh = Ah_g + (size_t)(bm + srow) * K + scol;
    const unsigned short* pAl = Al_g + (size_t)(bm + srow) * K + scol;
    const unsigned short* pBh = Bh_g + (size_t)(bn + srow) * K + scol;
    const unsigned short* pBl = Bl_g + (size_t)(bn + srow) * K + scol;
    unsigned short* dA0 = Ah + wave * 1024;
    unsigned short* dA1 = Al + wave * 1024;
    unsigned short* dB0 = Bh + wave * 1024;
    unsigned short* dB1 = Bl + wave * 1024;
    size_t rstep = (size_t)16 * K;

    f32x4 acc[4][4] = {};

    for (int k0 = 0; k0 < K; k0 += 32) {
        gl16(pAh + k0,         dA0);
        gl16(pAh + k0 + rstep, dA0 + 512);
        gl16(pAl + k0,         dA1);
        gl16(pAl + k0 + rstep, dA1 + 512);
        gl16(pBh + k0,         dB0);
        gl16(pBh + k0 + rstep, dB0 + 512);
        gl16(pBl + k0,         dB1);
        gl16(pBl + k0 + rstep, dB1 + 512);
        __syncthreads();

        bf16x8 fbh[4], fbl[4];
        #pragma unroll
        for (int nt = 0; nt < 4; ++nt) {
            fbh[nt] = *(const bf16x8*)&Bh[(wn + nt * 16 + ln) * 32 + quad * 8];
            fbl[nt] = *(const bf16x8*)&Bl[(wn + nt * 16 + ln) * 32 + quad * 8];
        }
        #pragma unroll
        for (int mt = 0; mt < 4; ++mt) {
            bf16x8 fah = *(const bf16x8*)&Ah[(wm + mt * 16 + ln) * 32 + quad * 8];
            bf16x8 fal = *(const bf16x8*)&Al[(wm + mt * 16 + ln) * 32 + quad * 8];
            #pragma unroll
            for (int nt = 0; nt < 4; ++nt) {
                acc[mt][nt] = __builtin_amdgcn_mfma_f32_16x16x32_bf16(fah, fbh[nt], acc[mt][nt], 0, 0, 0);
                acc[mt][nt] = __builtin_amdgcn_mfma_f32_16x16x32_bf16(fah, fbl[nt], acc[mt][nt], 0, 0, 0);
                acc[mt][nt] = __builtin_amdgcn_mfma_f32_16x16x32_bf16(fal, fbh[nt], acc[mt][nt], 0, 0, 0);
            }
        }
        __syncthreads();
    }

    // epilogue: D row = quad*4 + i, col = ln
    #pragma unroll
    for (int mt = 0; mt < 4; ++mt) {
        #pragma unroll
        for (int i = 0; i < 4; ++i) {
            int r = bm + wm + mt * 16 + quad * 4 + i;
            if (r >= M) continue;
            #pragma unroll
            for (int nt = 0; nt < 4; ++nt) {
                int c = bn + wn + nt * 16 + ln;
                float v = acc[mt][nt][i] + bias[c];
                if (OP == 0) {
                    Cf[(size_t)r * N + c] = v;
                } else if (OP == 1) {
                    v = 0.5f * v * (1.f + erff(v * 0.70710678118654752f));
                    unsigned short h, l;
                    split_bf16(v, h, l);
                    Ch[(size_t)r * N + c] = h;
                    Cl[(size_t)r * N + c] = l;
                } else {
                    Cf[(size_t)r * N + c] = v + R[(size_t)r * N + c];
                }
            }
        }
    }
}

// ---------------- flash attention (fp32), split-bf16 output -----------------
__global__ __launch_bounds__(256)
void attn_k(const float* __restrict__ QKV, unsigned short* __restrict__ Oh,
            unsigned short* __restrict__ Ol)
{
    const int T = 577;
    int img = blockIdx.z, head = blockIdx.y;
    int q0 = blockIdx.x * 16;
    const float* base = QKV + (size_t)img * T * 2304;
    __shared__ float Ks[64][68];
    __shared__ float Vs[64][68];
    __shared__ float Ps[16][68];
    int tid = threadIdx.x;
    int qi = tid >> 4, g = tid & 15;
    int tok = q0 + qi;
    float4 qreg[16];
    if (tok < T) {
        const float* qp = base + (size_t)tok * 2304 + head * 64;
        #pragma unroll
        for (int t = 0; t < 16; ++t) {
            float4 v = *(const float4*)(qp + t * 4);
            qreg[t] = make_float4(v.x * 0.125f, v.y * 0.125f, v.z * 0.125f, v.w * 0.125f);
        }
    } else {
        #pragma unroll
        for (int t = 0; t < 16; ++t) qreg[t] = make_float4(0, 0, 0, 0);
    }
    float m = -1e30f, l = 0.f;
    float4 o = make_float4(0, 0, 0, 0);
    for (int c0 = 0; c0 < T; c0 += 64) {
        int nk = min(64, T - c0);
        #pragma unroll
        for (int h = 0; h < 4; ++h) {
            int lin = tid + 256 * h;
            int r = lin >> 4, c = (lin & 15) * 4;
            float4 kv = make_float4(0, 0, 0, 0), vv = make_float4(0, 0, 0, 0);
            if (r < nk) {
                const float* kp = base + (size_t)(c0 + r) * 2304 + 768 + head * 64 + c;
                kv = *(const float4*)kp;
                vv = *(const float4*)(kp + 768);
            }
            *(float4*)&Ks[r][c] = kv;
            *(float4*)&Vs[r][c] = vv;
        }
        __syncthreads();
        float s[4];
        #pragma unroll
        for (int j = 0; j < 4; ++j) {
            int kj = g + 16 * j;
            float acc = 0.f;
            #pragma unroll
            for (int t = 0; t < 16; ++t) {
                float4 k4 = *(const float4*)&Ks[kj][t * 4];
                acc = fmaf(qreg[t].x, k4.x, acc);
                acc = fmaf(qreg[t].y, k4.y, acc);
                acc = fmaf(qreg[t].z, k4.z, acc);
                acc = fmaf(qreg[t].w, k4.w, acc);
            }
            s[j] = (kj < nk) ? acc : -1e30f;
        }
        float mc = fmaxf(fmaxf(s[0], s[1]), fmaxf(s[2], s[3]));
        for (int off = 8; off; off >>= 1) mc = fmaxf(mc, __shfl_xor(mc, off, 16));
        float mnew = fmaxf(m, mc);
        float alpha = __expf(m - mnew);
        float p[4];
        float rsum = 0.f;
        #pragma unroll
        for (int j = 0; j < 4; ++j) { p[j] = __expf(s[j] - mnew); rsum += p[j]; }
        for (int off = 8; off; off >>= 1) rsum += __shfl_xor(rsum, off, 16);
        m = mnew; l = l * alpha + rsum;
        o.x *= alpha; o.y *= alpha; o.z *= alpha; o.w *= alpha;
        #pragma unroll
        for (int j = 0; j < 4; ++j) Ps[qi][g + 16 * j] = p[j];
        __syncthreads();
        #pragma unroll 8
        for (int kj = 0; kj < 64; ++kj) {
            float pv = Ps[qi][kj];
            float4 v4 = *(const float4*)&Vs[kj][g * 4];
            o.x = fmaf(pv, v4.x, o.x);
            o.y = fmaf(pv, v4.y, o.y);
            o.z = fmaf(pv, v4.z, o.z);
            o.w = fmaf(pv, v4.w, o.w);
        }
        __syncthreads();
    }
    if (tok < T) {
        float inv = 1.f / l;
        size_t idx = (size_t)(img * 577 + tok) * 768 + head * 64 + g * 4;
        unsigned short h0, h1, h2, h3, l0, l1, l2, l3;
        split_bf16(o.x * inv, h0, l0); split_bf16(o.y * inv, h1, l1);
        split_bf16(o.z * inv, h2, l2); split_bf16(o.w * inv, h3, l3);
        *(ushort4*)&Oh[idx] = make_ushort4(h0, h1, h2, h3);
        *(ushort4*)&Ol[idx] = make_ushort4(l0, l1, l2, l3);
    }
}

// ---------------- final LN(cls) + cosine loss -------------------------------
__global__ __launch_bounds__(256)
void final_k(const float* __restrict__ X, const float* __restrict__ g,
             const float* __restrict__ b, float* __restrict__ out)
{
    __shared__ float F[4][768];
    __shared__ float rs[4], rss[4];
    __shared__ float rd[4], rna[4], rnb[4];
    __shared__ float cosv[2];
    int tid = threadIdx.x;
    for (int rr = 0; rr < 4; ++rr) {
        const float* x = X + (size_t)rr * 577 * 768;
        float v0 = x[tid], v1 = x[tid + 256], v2 = x[tid + 512];
        float s = v0 + v1 + v2;
        float ss = v0 * v0 + v1 * v1 + v2 * v2;
        for (int off = 32; off; off >>= 1) {
            s  += __shfl_xor(s, off, 64);
            ss += __shfl_xor(ss, off, 64);
        }
        if ((tid & 63) == 0) { rs[tid >> 6] = s; rss[tid >> 6] = ss; }
        __syncthreads();
        s  = rs[0] + rs[1] + rs[2] + rs[3];
        ss = rss[0] + rss[1] + rss[2] + rss[3];
        float mu  = s * (1.f / 768.f);
        float var = ss * (1.f / 768.f) - mu * mu;
        float inv = rsqrtf(var + 1e-6f);
        F[rr][tid]       = (v0 - mu) * inv * g[tid]       + b[tid];
        F[rr][tid + 256] = (v1 - mu) * inv * g[tid + 256] + b[tid + 256];
        F[rr][tid + 512] = (v2 - mu) * inv * g[tid + 512] + b[tid + 512];
        __syncthreads();
    }
    for (int bb = 0; bb < 2; ++bb) {
        float d = 0.f, na = 0.f, nb = 0.f;
        for (int u = tid; u < 768; u += 256) {
            float fa = F[bb][u], fb = F[bb + 2][u];
            d += fa * fb; na += fa * fa; nb += fb * fb;
        }
        for (int off = 32; off; off >>= 1) {
            d  += __shfl_xor(d, off, 64);
            na += __shfl_xor(na, off, 64);
            nb += __shfl_xor(nb, off, 64);
        }
        if ((tid & 63) == 0) { rd[tid >> 6] = d; rna[tid >> 6] = na; rnb[tid >> 6] = nb; }
        __syncthreads();
        if (tid == 0) {
            float D  = rd[0] + rd[1] + rd[2] + rd[3];
            float NA = sqrtf(rna[0] + rna[1] + rna[2] + rna[3]);
            float NB = sqrtf(rnb[0] + rnb[1] + rnb[2] + rnb[3]);
            cosv[bb] = D / (fmaxf(NA, 1e-8f) * fmaxf(NB, 1e-8f));
        }
        __syncthreads();
    }
    if (tid == 0) out[0] = 1.f - 0.5f * (cosv[0] + cosv[1]);
}

// ---------------- host orchestration ----------------------------------------
extern "C" void kernel_launch(void* const* d_in, const int* in_sizes, int n_in,
                              void* d_out, int out_size, void* d_ws, size_t ws_size,
                              hipStream_t stream)
{
    const float* logits  = (const float*)d_in[0];
    const int*   truem   = (const int*)d_in[1];
    const float* patch_w = (const float*)d_in[2];
    const float* patch_b = (const float*)d_in[3];
    const float* cls_tok = (const float*)d_in[4];
    const float* pos_emb = (const float*)d_in[5];
    const float* ln1_g   = (const float*)d_in[6];
    const float* ln1_b   = (const float*)d_in[7];
    const float* qkv_w   = (const float*)d_in[8];
    const float* qkv_b   = (const float*)d_in[9];
    const float* proj_w  = (const float*)d_in[10];
    const float* proj_b  = (const float*)d_in[11];
    const float* ln2_g   = (const float*)d_in[12];
    const float* ln2_b   = (const float*)d_in[13];
    const float* fc1_w   = (const float*)d_in[14];
    const float* fc1_b   = (const float*)d_in[15];
    const float* fc2_w   = (const float*)d_in[16];
    const float* fc2_b   = (const float*)d_in[17];
    const float* norm_g  = (const float*)d_in[18];
    const float* norm_b  = (const float*)d_in[19];

    char* p = (char*)d_ws;
    float* X             = (float*)(p + 0);              //  7,090,176 B (2308x768 f32)
    float* QKV           = (float*)(p + 7090176);        // 21,270,528 B (2308x2304 f32)
    unsigned short* qkvTh = (unsigned short*)(p + 28360704);  // 2304x768
    unsigned short* qkvTl = (unsigned short*)(p + 31899648);
    unsigned short* projTh= (unsigned short*)(p + 35438592);  // 768x768
    unsigned short* projTl= (unsigned short*)(p + 36618240);
    unsigned short* fc1Th = (unsigned short*)(p + 37797888);  // 3072x768
    unsigned short* fc1Tl = (unsigned short*)(p + 42516480);
    unsigned short* fc2Th = (unsigned short*)(p + 47235072);  // 768x3072
    unsigned short* fc2Tl = (unsigned short*)(p + 51953664);
    unsigned short* Hh    = (unsigned short*)(p + 56672256);  // 2432x768
    unsigned short* Hl    = (unsigned short*)(p + 60407808);
    unsigned short* Oh    = (unsigned short*)(p + 64143360);  // 2432x768
    unsigned short* Ol    = (unsigned short*)(p + 67878912);
    unsigned short* MIDh  = (unsigned short*)(p + 71614464);  // 2432x3072
    unsigned short* MIDl  = (unsigned short*)(p + 86556672);
    // EDT/patch phase overlays (dead before layer loop uses the regions):
    float* g2o   = (float*)MIDh;
    float* g2z   = g2o + 589824;
    float* sdm   = (float*)MIDl;
    unsigned short* pvh = Hh;
    unsigned short* pvl = Hl;
    float* Weff  = (float*)Oh;           // 256x768 f32
    unsigned short* WeffTh = qkvTh;      // 768x256
    unsigned short* WeffTl = qkvTl;
    float* tokb  = QKV;                  // 2304x768 f32

    edt_rows_k<<<1536, 64, 0, stream>>>(logits, truem, g2o, g2z);
    edt_cols_k<<<dim3(48, 4), 256, 0, stream>>>(g2o, g2z, sdm);
    weff_k<<<768, 256, 0, stream>>>(patch_w, Weff);
    tconv_k<<<192, 256, 0, stream>>>(Weff, WeffTh, WeffTl, 256, 768);
    pvec_split_k<<<2304, 256, 0, stream>>>(sdm, pvh, pvl);
    gemm_bt_k<0><<<dim3(6, 18), 256, 0, stream>>>(pvh, pvl, WeffTh, WeffTl, patch_b,
                                                  nullptr, tokb, nullptr, nullptr,
                                                  2304, 768, 256);
    addpos_k<<<6924, 256, 0, stream>>>(tokb, cls_tok, pos_emb, X);

    for (int l = 0; l < 12; ++l) {
        wconv_layer_k<<<6912, 256, 0, stream>>>(
            qkv_w + (size_t)l * 768 * 2304, proj_w + (size_t)l * 768 * 768,
            fc1_w + (size_t)l * 768 * 3072, fc2_w + (size_t)l * 3072 * 768,
            qkvTh, qkvTl, projTh, projTl, fc1Th, fc1Tl, fc2Th, fc2Tl);
        ln_split_k<<<2308, 256, 0, stream>>>(X, ln1_g + l * 768, ln1_b + l * 768, Hh, Hl);
        gemm_bt_k<0><<<dim3(18, 19), 256, 0, stream>>>(Hh, Hl, qkvTh, qkvTl,
                                                       qkv_b + l * 2304, nullptr, QKV,
                                                       nullptr, nullptr, 2308, 2304, 768);
        attn_k<<<dim3(37, 12, 4), 256, 0, stream>>>(QKV, Oh, Ol);
        gemm_bt_k<2><<<dim3(6, 19), 256, 0, stream>>>(Oh, Ol, projTh, projTl,
                                                      proj_b + l * 768, X, X,
                                                      nullptr, nullptr, 2308, 768, 768);
        ln_split_k<<<2308, 256, 0, stream>>>(X, ln2_g + l * 768, ln2_b + l * 768, Hh, Hl);
        gemm_bt_k<1><<<dim3(24, 19), 256, 0, stream>>>(Hh, Hl, fc1Th, fc1Tl,
                                                       fc1_b + l * 3072, nullptr, nullptr,
                                                       MIDh, MIDl, 2308, 3072, 768);
        gemm_bt_k<2><<<dim3(6, 19), 256, 0, stream>>>(MIDh, MIDl, fc2Th, fc2Tl,
                                                      fc2_b + l * 768, X, X,
                                                      nullptr, nullptr, 2308, 768, 3072);
    }
    final_k<<<1, 256, 0, stream>>>(X, norm_g, norm_b, (float*)d_out);
}